// Round 5
// baseline (393.985 us; speedup 1.0000x reference)
//
#include <hip/hip_runtime.h>
#include <hip/hip_bf16.h>
#include <stdint.h>

#define G_    1024
#define NPG   64
#define EPG   256
#define N_    (G_*NPG)     // 65536
#define E_    (G_*EPG)     // 262144
#define IN_CH 768
#define CH    128
#define KSEL  128
#define HID   512          // 4*CH

// ---- output layout (element offsets, all float32) ----
#define NCH  (N_*CH)       // 8388608
#define GK   (G_*KSEL)     // 131072
#define OFF0 0
#define OFF1 (OFF0 + NCH)
#define OFF2 (OFF1 + 2*GK)
#define OFF3 (OFF2 + GK)
#define OFF4 (OFF3 + GK)
#define OFF5 (OFF4 + N_)
#define OFF6 (OFF5 + NCH)
#define OFF7 (OFF6 + 2*GK)
#define OFF8 (OFF7 + GK)
#define OFF9 (OFF8 + GK)
#define OFF10 (OFF9 + N_)

typedef unsigned short u16;
typedef unsigned int   u32;
typedef __attribute__((ext_vector_type(8))) short bf16x8;
typedef __attribute__((ext_vector_type(4))) float f32x4;

__device__ __forceinline__ u16 f2bf(float x) {
    union { float f; u32 u; } v; v.f = x;
    u32 r = v.u + 0x7fffu + ((v.u >> 16) & 1u);   // RNE
    return (u16)(r >> 16);
}
__device__ __forceinline__ float bf2f(u32 h) {
    union { u32 u; float f; } v; v.u = h << 16; return v.f;
}

__global__ void k_deg(const int* __restrict__ ei, const float* __restrict__ ea,
                      float* __restrict__ deg) {
    int e = blockIdx.x * 256 + threadIdx.x;
    if (e < E_) atomicAdd(&deg[ei[E_ + e]], ea[e]);
}

__global__ void k_dis(float* __restrict__ deg) {
    int i = blockIdx.x * 256 + threadIdx.x;
    if (i < N_) { float d = deg[i]; deg[i] = d > 0.f ? 1.0f / sqrtf(d) : 0.f; }
}

__global__ void k_norm(const int* __restrict__ ei, const float* __restrict__ ea,
                       const float* __restrict__ dis, float* __restrict__ norm) {
    int e = blockIdx.x * 256 + threadIdx.x;
    if (e < E_) norm[e] = dis[ei[e]] * ea[e] * dis[ei[E_ + e]];
}

// Build TRANSPOSED bf16 weights:
//  WV1t (256x768): row c holds col c of [W1|V1]
//  WV2t (256x128): row c holds col c of [W2|V2]
//  Mwt (1024x128): row c, c<512 -> mw1[:,c] rows 0..127 ; c>=512 -> mw1 rows 128..255 col c-512
__global__ void k_concat(const float* __restrict__ W1, const float* __restrict__ V1,
                         const float* __restrict__ W2, const float* __restrict__ V2,
                         const float* __restrict__ mw1,
                         u16* __restrict__ WV1t, u16* __restrict__ WV2t,
                         u16* __restrict__ Mwt) {
    int i = blockIdx.x * 256 + threadIdx.x;
    if (i < 256 * IN_CH) {
        int c = i / IN_CH, r = i - c * IN_CH;
        WV1t[i] = f2bf(c < CH ? W1[r*CH + c] : V1[r*CH + (c - CH)]);
    }
    if (i < 256 * CH) {
        int c = i >> 7, r = i & 127;
        WV2t[i] = f2bf(c < CH ? W2[r*CH + c] : V2[r*CH + (c - CH)]);
    }
    if (i < 1024 * CH) {
        int c = i >> 7, r = i & 127;
        Mwt[i] = f2bf(c < HID ? mw1[r*HID + c] : mw1[(CH + r)*HID + (c - HID)]);
    }
}

// Barrier-free, LDS-free MFMA GEMM: C(Mx Nn) = A(MxK) @ Bt(Nn x K)^T.
// Tile 128x128 per block, 4 waves (2x2), each wave 64x64.
// A/B fragments loaded straight from global: per fragment-instr the wave's
// 16 rows x 4 kq-groups consume 16 full 128B lines (fully coalesced).
// B is weights (<=384 KB) -> L2-resident. No __syncthreads anywhere:
// waves pipeline independently; TLP hides HBM latency.
// Grid: 1D, bid -> bn = bid % nyb, bm = bid / nyb (consecutive blocks share bm).
template<int K, int A_F32, int C_BF16>
__global__ __launch_bounds__(256) void gemm_nolds(const void* __restrict__ Ap,
        const u16* __restrict__ Bt, void* __restrict__ Cp, int Nn, int nyb) {
    const int t = threadIdx.x;
    const int lane = t & 63, w = t >> 6;
    const int wr = (w >> 1) << 6, wc = (w & 1) << 6;
    const int bid = blockIdx.x;
    const size_t bm = (size_t)(bid / nyb) * 128;
    const size_t bn = (size_t)(bid % nyb) * 128;
    const int r16 = lane & 15, kq = lane >> 4;

    f32x4 acc[4][4];
    #pragma unroll
    for (int m = 0; m < 4; ++m)
        #pragma unroll
        for (int n = 0; n < 4; ++n)
            acc[m][n] = (f32x4){0.f, 0.f, 0.f, 0.f};

    const int nk = K >> 5;
    #pragma unroll 2
    for (int ki = 0; ki < nk; ++ki) {
        const int k0 = ki << 5;
        bf16x8 a[4], b[4];
        #pragma unroll
        for (int m = 0; m < 4; ++m) {
            size_t row = bm + wr + m * 16 + r16;
            if (A_F32) {
                const float* ap = (const float*)Ap + row * (size_t)K + k0 + kq * 8;
                float4 lo = *(const float4*)ap;
                float4 hi = *(const float4*)(ap + 4);
                union { bf16x8 v; u16 s[8]; } pk;
                pk.s[0]=f2bf(lo.x); pk.s[1]=f2bf(lo.y); pk.s[2]=f2bf(lo.z); pk.s[3]=f2bf(lo.w);
                pk.s[4]=f2bf(hi.x); pk.s[5]=f2bf(hi.y); pk.s[6]=f2bf(hi.z); pk.s[7]=f2bf(hi.w);
                a[m] = pk.v;
            } else {
                a[m] = *(const bf16x8*)((const u16*)Ap + row * (size_t)K + k0 + kq * 8);
            }
        }
        #pragma unroll
        for (int n = 0; n < 4; ++n) {
            size_t col = bn + wc + n * 16 + r16;
            b[n] = *(const bf16x8*)(Bt + col * (size_t)K + k0 + kq * 8);
        }
        #pragma unroll
        for (int m = 0; m < 4; ++m)
            #pragma unroll
            for (int n = 0; n < 4; ++n)
                acc[m][n] = __builtin_amdgcn_mfma_f32_16x16x32_bf16(a[m], b[n], acc[m][n], 0, 0, 0);
    }

    // C/D layout: col = lane&15, row = (lane>>4)*4 + reg
    #pragma unroll
    for (int m = 0; m < 4; ++m) {
        #pragma unroll
        for (int j = 0; j < 4; ++j) {
            size_t row = bm + wr + m * 16 + kq * 4 + j;
            #pragma unroll
            for (int n = 0; n < 4; ++n) {
                size_t col = bn + wc + n * 16 + r16;
                if (C_BF16) ((u16*)Cp)[row * Nn + col] = f2bf(acc[m][n][j]);
                else        ((float*)Cp)[row * Nn + col] = acc[m][n][j];
            }
        }
    }
}

// Fused per-graph aggregation + epilogue.
// agg[c][ch] = sum_r A[r][c] * m[r][ch], via dense 64x64 LDS adjacency + MFMA.
// Then out = relu(agg + v + bias).  B holds [m|v] (N x 256 f32).
template<int LAYER>
__global__ __launch_bounds__(256) void k_agg(const int* __restrict__ ei,
        const float* __restrict__ norm, const float* __restrict__ B,
        const float* __restrict__ bias, float* __restrict__ out0,
        float* __restrict__ out5, u16* __restrict__ xb) {
    __shared__ float A_s[64 * 65];   // [r][c], padded
    __shared__ u16   Ms[64 * 132];   // m bf16 [r][ch], padded
    const int g = blockIdx.x, t = threadIdx.x;
    const int lane = t & 63, w = t >> 6;
    const int r16 = lane & 15, kq = lane >> 4;
    const size_t nbase = (size_t)g * 64;

    #pragma unroll
    for (int i = t; i < 64 * 65; i += 256) A_s[i] = 0.f;
    #pragma unroll
    for (int i = t; i < 64 * 32; i += 256) {
        int row = i >> 5, c4 = (i & 31) << 2;
        float4 mv = *(const float4*)(B + (nbase + row) * 256 + c4);
        union { uint2 d; u16 s[4]; } p;
        p.s[0] = f2bf(mv.x); p.s[1] = f2bf(mv.y);
        p.s[2] = f2bf(mv.z); p.s[3] = f2bf(mv.w);
        *(uint2*)&Ms[row * 132 + c4] = p.d;
    }
    __syncthreads();
    {   // scatter 256 edges into A_s[r][c] (duplicates possible -> atomic)
        int e = g * 256 + t;
        int r = ei[e] & 63, c = ei[E_ + e] & 63;
        atomicAdd(&A_s[r * 65 + c], norm[e]);
    }
    __syncthreads();

    const int n0 = w * 32;           // wave's ch chunk
    f32x4 acc[4][2];
    #pragma unroll
    for (int mt = 0; mt < 4; ++mt)
        #pragma unroll
        for (int nt = 0; nt < 2; ++nt)
            acc[mt][nt] = (f32x4){0.f, 0.f, 0.f, 0.f};

    union bfr { bf16x8 v; u16 s[8]; };
    #pragma unroll
    for (int ks = 0; ks < 2; ++ks) {
        bfr a[4], b[2];
        #pragma unroll
        for (int mt = 0; mt < 4; ++mt)
            #pragma unroll
            for (int i = 0; i < 8; ++i)
                a[mt].s[i] = f2bf(A_s[(ks*32 + kq*8 + i) * 65 + mt*16 + r16]);
        #pragma unroll
        for (int nt = 0; nt < 2; ++nt)
            #pragma unroll
            for (int i = 0; i < 8; ++i)
                b[nt].s[i] = Ms[(ks*32 + kq*8 + i) * 132 + n0 + nt*16 + r16];
        #pragma unroll
        for (int mt = 0; mt < 4; ++mt)
            #pragma unroll
            for (int nt = 0; nt < 2; ++nt)
                acc[mt][nt] = __builtin_amdgcn_mfma_f32_16x16x32_bf16(a[mt].v, b[nt].v, acc[mt][nt], 0, 0, 0);
    }
    // epilogue: C row = output node (c), col = ch
    #pragma unroll
    for (int mt = 0; mt < 4; ++mt) {
        #pragma unroll
        for (int j = 0; j < 4; ++j) {
            int c = mt * 16 + kq * 4 + j;
            size_t node = nbase + c;
            #pragma unroll
            for (int nt = 0; nt < 2; ++nt) {
                int ch = n0 + nt * 16 + r16;
                float v = B[node * 256 + 128 + ch] + bias[ch];
                float r = fmaxf(acc[mt][nt][j] + v, 0.f);
                if (LAYER == 1) {
                    xb[node * 128 + ch] = f2bf(r);
                } else {
                    out0[node * 128 + ch] = r;
                    out5[node * 128 + ch] = r;
                    xb[node * 128 + ch] = f2bf(r);
                }
            }
        }
    }
}

// pred[e] = mb2 + sum_j relu(P[row][j] + Q[col][j] + mb1[j]) * mw2[j]
// PQ: Nx1024 bf16, P = [0,512), Q = [512,1024). One wave per edge.
__global__ __launch_bounds__(256) void k_edge(const int* __restrict__ ei,
        const u16* __restrict__ PQ, const float* __restrict__ mb1,
        const float* __restrict__ mw2, const float* __restrict__ mb2,
        float* __restrict__ pred) {
    int wid = threadIdx.x >> 6, lane = threadIdx.x & 63;
    int e = blockIdx.x * 4 + wid;
    int r = ei[e], c = ei[E_ + e];
    uint4 up = *(const uint4*)(PQ + (size_t)r * 1024 + lane * 8);
    uint4 uq = *(const uint4*)(PQ + (size_t)c * 1024 + 512 + lane * 8);
    float4 b0 = *(const float4*)(mb1 + lane * 8);
    float4 b1 = *(const float4*)(mb1 + lane * 8 + 4);
    float4 w0 = *(const float4*)(mw2 + lane * 8);
    float4 w1 = *(const float4*)(mw2 + lane * 8 + 4);
    u32 pu[4] = {up.x, up.y, up.z, up.w};
    u32 qu[4] = {uq.x, uq.y, uq.z, uq.w};
    float bb[8] = {b0.x,b0.y,b0.z,b0.w,b1.x,b1.y,b1.z,b1.w};
    float ww[8] = {w0.x,w0.y,w0.z,w0.w,w1.x,w1.y,w1.z,w1.w};
    float s = 0.f;
    #pragma unroll
    for (int k = 0; k < 4; ++k) {
        float p0 = bf2f(pu[k] & 0xffffu), p1 = bf2f(pu[k] >> 16);
        float q0 = bf2f(qu[k] & 0xffffu), q1 = bf2f(qu[k] >> 16);
        float h0 = fmaxf(p0 + q0 + bb[2*k],     0.f);
        float h1 = fmaxf(p1 + q1 + bb[2*k + 1], 0.f);
        s += h0 * ww[2*k] + h1 * ww[2*k + 1];
    }
    #pragma unroll
    for (int m = 32; m >= 1; m >>= 1) s += __shfl_xor(s, m, 64);
    if (lane == 0) pred[e] = s + mb2[0];
}

// one block per graph: stable bitonic sort (desc by pred, ties by idx asc),
// then write causal/conf gathers + the full pred copy.
__global__ __launch_bounds__(256) void k_sort(const float* __restrict__ pred,
        const int* __restrict__ ei, const float* __restrict__ ea,
        float* __restrict__ out) {
    __shared__ float key[256];
    __shared__ int   idx[256];
    int g = blockIdx.x, t = threadIdx.x;
    int ebase = g * EPG;
    float p = pred[ebase + t];
    key[t] = p; idx[t] = t;
    for (int k2 = 2; k2 <= 256; k2 <<= 1) {
        for (int j = k2 >> 1; j >= 1; j >>= 1) {
            __syncthreads();
            int ixj = t ^ j;
            if (ixj > t) {
                float ka = key[t], kb = key[ixj];
                int   ia = idx[t], ib = idx[ixj];
                bool up = ((t & k2) == 0);
                bool a_before_b = (ka > kb) || (ka == kb && ia < ib);
                bool do_swap = up ? !a_before_b : a_before_b;
                if (do_swap) { key[t] = kb; key[ixj] = ka; idx[t] = ib; idx[ixj] = ia; }
            }
        }
    }
    __syncthreads();
    int el = idx[t];
    int eg = ebase + el;
    float pv = key[t];
    float r = (float)ei[eg];
    float c = (float)ei[E_ + eg];
    float av = ea[eg];
    if (t < KSEL) {
        int oo = g * KSEL + t;
        out[OFF1 + oo]      = r;
        out[OFF1 + GK + oo] = c;
        out[OFF2 + oo]      = av;
        out[OFF3 + oo]      = pv;
    } else {
        int oo = g * KSEL + (t - KSEL);
        out[OFF6 + oo]      = r;
        out[OFF6 + GK + oo] = c;
        out[OFF7 + oo]      = av;
        out[OFF8 + oo]      = -pv;
    }
    out[OFF10 + ebase + t] = p;
}

__global__ void k_batch(const int* __restrict__ batch, float* __restrict__ out) {
    int i = blockIdx.x * 256 + threadIdx.x;
    if (i < N_) { float b = (float)batch[i]; out[OFF4 + i] = b; out[OFF9 + i] = b; }
}

extern "C" void kernel_launch(void* const* d_in, const int* in_sizes, int n_in,
                              void* d_out, int out_size, void* d_ws, size_t ws_size,
                              hipStream_t stream) {
    const float* x     = (const float*)d_in[0];
    const int*   ei    = (const int*)  d_in[1];
    const float* ea    = (const float*)d_in[2];
    const int*   batch = (const int*)  d_in[3];
    const float* W1    = (const float*)d_in[4];
    const float* V1    = (const float*)d_in[5];
    const float* b1    = (const float*)d_in[6];
    const float* W2    = (const float*)d_in[7];
    const float* V2    = (const float*)d_in[8];
    const float* b2    = (const float*)d_in[9];
    const float* mw1   = (const float*)d_in[10];
    const float* mb1   = (const float*)d_in[11];
    const float* mw2   = (const float*)d_in[12];
    const float* mb2   = (const float*)d_in[13];
    float* out = (float*)d_out;

    char* ws = (char*)d_ws;
    size_t o = 0;
    float* deg  = (float*)(ws + o); o += (size_t)N_ * 4;          // 256 KB
    float* norm = (float*)(ws + o); o += (size_t)E_ * 4;          // 1 MB
    float* pred = (float*)(ws + o); o += (size_t)E_ * 4;          // 1 MB
    u16* WV1t   = (u16*)(ws + o);   o += (size_t)256 * IN_CH * 2; // 384 KB
    u16* WV2t   = (u16*)(ws + o);   o += (size_t)256 * CH * 2;    // 64 KB
    u16* Mwt    = (u16*)(ws + o);   o += (size_t)1024 * CH * 2;   // 256 KB
    u16* x2b    = (u16*)(ws + o);   o += (size_t)N_ * CH * 2;     // 16 MB
    char* pqb   = ws + o;                                         // PQ region start
    u16* x1b    = (u16*)(ws + o);   o += (size_t)N_ * CH * 2;     // 16 MB
    float* B    = (float*)(ws + o); o += (size_t)N_ * 256 * 4;    // 64 MB
    o += (size_t)48 << 20;                                        // pad so PQ fits
    u16* PQ = (u16*)pqb;   // N x 1024 bf16 = 128 MB, aliases x1b/B/pad (dead at GEMM3)

    // degree / norm / weights
    hipMemsetAsync(deg, 0, (size_t)N_ * 4, stream);
    k_deg <<<E_/256, 256, 0, stream>>>(ei, ea, deg);
    k_dis <<<N_/256, 256, 0, stream>>>(deg);
    k_norm<<<E_/256, 256, 0, stream>>>(ei, ea, deg, norm);
    k_concat<<<768, 256, 0, stream>>>(W1, V1, W2, V2, mw1, WV1t, WV2t, Mwt);

    // layer 1: B = [m|v] = x @ [W1|V1]  (A fp32 converted in fragment load)
    gemm_nolds<IN_CH,1,0><<<(N_/128)*2, 256, 0, stream>>>(x, WV1t, B, 256, 2);
    k_agg<1><<<G_, 256, 0, stream>>>(ei, norm, B, b1, nullptr, nullptr, x1b);
    // layer 2
    gemm_nolds<CH,0,0><<<(N_/128)*2, 256, 0, stream>>>(x1b, WV2t, B, 256, 2);
    k_agg<2><<<G_, 256, 0, stream>>>(ei, norm, B, b2, out + OFF0, out + OFF5, x2b);
    // edge MLP hoisted to nodes: PQ = x2 @ Mw (N x 1024), bf16 out
    gemm_nolds<CH,0,1><<<(N_/128)*8, 256, 0, stream>>>(x2b, Mwt, PQ, 1024, 8);
    k_edge<<<E_/4, 256, 0, stream>>>(ei, PQ, mb1, mw2, mb2, pred);
    // per-graph top-K partition + outputs
    k_sort<<<G_, 256, 0, stream>>>(pred, ei, ea, out);
    k_batch<<<N_/256, 256, 0, stream>>>(batch, out);
}

// Round 6
// 275.362 us; speedup vs baseline: 1.4308x; 1.4308x over previous
//
#include <hip/hip_runtime.h>
#include <hip/hip_bf16.h>
#include <stdint.h>

#define G_    1024
#define NPG   64
#define EPG   256
#define N_    (G_*NPG)     // 65536
#define E_    (G_*EPG)     // 262144
#define IN_CH 768
#define CH    128
#define KSEL  128
#define HID   512          // 4*CH

// ---- output layout (element offsets, all float32) ----
#define NCH  (N_*CH)       // 8388608
#define GK   (G_*KSEL)     // 131072
#define OFF0 0
#define OFF1 (OFF0 + NCH)
#define OFF2 (OFF1 + 2*GK)
#define OFF3 (OFF2 + GK)
#define OFF4 (OFF3 + GK)
#define OFF5 (OFF4 + N_)
#define OFF6 (OFF5 + NCH)
#define OFF7 (OFF6 + 2*GK)
#define OFF8 (OFF7 + GK)
#define OFF9 (OFF8 + GK)
#define OFF10 (OFF9 + N_)

typedef unsigned short u16;
typedef unsigned int   u32;
typedef __attribute__((ext_vector_type(8))) short bf16x8;
typedef __attribute__((ext_vector_type(4))) float f32x4;

__device__ __forceinline__ u16 f2bf(float x) {
    union { float f; u32 u; } v; v.f = x;
    u32 r = v.u + 0x7fffu + ((v.u >> 16) & 1u);   // RNE
    return (u16)(r >> 16);
}
__device__ __forceinline__ float bf2f(u32 h) {
    union { u32 u; float f; } v; v.u = h << 16; return v.f;
}

__global__ void k_deg(const int* __restrict__ ei, const float* __restrict__ ea,
                      float* __restrict__ deg) {
    int e = blockIdx.x * 256 + threadIdx.x;
    if (e < E_) atomicAdd(&deg[ei[E_ + e]], ea[e]);
}

__global__ void k_dis(float* __restrict__ deg) {
    int i = blockIdx.x * 256 + threadIdx.x;
    if (i < N_) { float d = deg[i]; deg[i] = d > 0.f ? 1.0f / sqrtf(d) : 0.f; }
}

__global__ void k_norm(const int* __restrict__ ei, const float* __restrict__ ea,
                       const float* __restrict__ dis, float* __restrict__ norm) {
    int e = blockIdx.x * 256 + threadIdx.x;
    if (e < E_) norm[e] = dis[ei[e]] * ea[e] * dis[ei[E_ + e]];
}

// Build TRANSPOSED bf16 weights:
//  WV1t (256x768): row c holds col c of [W1|V1]
//  WV2t (256x128): row c holds col c of [W2|V2]
//  Mwt (1024x128): row c, c<512 -> mw1[:,c] rows 0..127 ; c>=512 -> mw1 rows 128..255 col c-512
__global__ void k_concat(const float* __restrict__ W1, const float* __restrict__ V1,
                         const float* __restrict__ W2, const float* __restrict__ V2,
                         const float* __restrict__ mw1,
                         u16* __restrict__ WV1t, u16* __restrict__ WV2t,
                         u16* __restrict__ Mwt) {
    int i = blockIdx.x * 256 + threadIdx.x;
    if (i < 256 * IN_CH) {
        int c = i / IN_CH, r = i - c * IN_CH;
        WV1t[i] = f2bf(c < CH ? W1[r*CH + c] : V1[r*CH + (c - CH)]);
    }
    if (i < 256 * CH) {
        int c = i >> 7, r = i & 127;
        WV2t[i] = f2bf(c < CH ? W2[r*CH + c] : V2[r*CH + (c - CH)]);
    }
    if (i < 1024 * CH) {
        int c = i >> 7, r = i & 127;
        Mwt[i] = f2bf(c < HID ? mw1[r*HID + c] : mw1[(CH + r)*HID + (c - HID)]);
    }
}

// bf16 MFMA GEMM: C(MxN) = A(MxK) @ Bt(NxK)^T.  Tile 128x128, BK=32, 256 thr = 4 waves.
// 2-phase double-buffered pipeline (round-4 version, GEMM1 = 122 us measured).
template<int A_F32, int C_BF16>
__global__ __launch_bounds__(256) void mfma_gemm(const void* __restrict__ Ap,
        const u16* __restrict__ Bt, void* __restrict__ Cp, int Nn, int K) {
    __shared__ u16 As[2][128 * 32];
    __shared__ u16 Bs[2][128 * 32];
    const int t = threadIdx.x;
    const int lane = t & 63, w = t >> 6;
    const int wr = (w >> 1) << 6, wc = (w & 1) << 6;
    const size_t bm = (size_t)blockIdx.x * 128;
    const size_t bn = (size_t)blockIdx.y * 128;
    const int r16 = lane & 15, kq = lane >> 4;
    const int row0 = t >> 2,          c0 = t & 3;
    const int row1 = (t + 256) >> 2,  c1 = (t + 256) & 3;

    float4 alo0, ahi0, alo1, ahi1;
    uint4  ab0, ab1;
    uint4  bb0, bb1;

    #define LOAD_TILE(k0)                                                           \
        do {                                                                        \
            if (A_F32) {                                                            \
                const float* ap0 = (const float*)Ap + (bm + row0) * (size_t)K + (k0) + c0 * 8; \
                alo0 = *(const float4*)ap0;  ahi0 = *(const float4*)(ap0 + 4);      \
                const float* ap1 = (const float*)Ap + (bm + row1) * (size_t)K + (k0) + c1 * 8; \
                alo1 = *(const float4*)ap1;  ahi1 = *(const float4*)(ap1 + 4);      \
            } else {                                                                \
                ab0 = *(const uint4*)((const u16*)Ap + (bm + row0) * (size_t)K + (k0) + c0 * 8); \
                ab1 = *(const uint4*)((const u16*)Ap + (bm + row1) * (size_t)K + (k0) + c1 * 8); \
            }                                                                       \
            bb0 = *(const uint4*)(Bt + (bn + row0) * (size_t)K + (k0) + c0 * 8);    \
            bb1 = *(const uint4*)(Bt + (bn + row1) * (size_t)K + (k0) + c1 * 8);    \
        } while (0)

    #define WRITE_TILE(buf)                                                         \
        do {                                                                        \
            int sc0 = c0 ^ (row0 & 3), sc1 = c1 ^ (row1 & 3);                       \
            uint4 va0, va1;                                                         \
            if (A_F32) {                                                            \
                union { uint4 q; u16 s[8]; } pk;                                    \
                pk.s[0]=f2bf(alo0.x); pk.s[1]=f2bf(alo0.y); pk.s[2]=f2bf(alo0.z); pk.s[3]=f2bf(alo0.w); \
                pk.s[4]=f2bf(ahi0.x); pk.s[5]=f2bf(ahi0.y); pk.s[6]=f2bf(ahi0.z); pk.s[7]=f2bf(ahi0.w); \
                va0 = pk.q;                                                         \
                pk.s[0]=f2bf(alo1.x); pk.s[1]=f2bf(alo1.y); pk.s[2]=f2bf(alo1.z); pk.s[3]=f2bf(alo1.w); \
                pk.s[4]=f2bf(ahi1.x); pk.s[5]=f2bf(ahi1.y); pk.s[6]=f2bf(ahi1.z); pk.s[7]=f2bf(ahi1.w); \
                va1 = pk.q;                                                         \
            } else { va0 = ab0; va1 = ab1; }                                        \
            *(uint4*)&As[buf][row0 * 32 + sc0 * 8] = va0;                           \
            *(uint4*)&Bs[buf][row0 * 32 + sc0 * 8] = bb0;                           \
            *(uint4*)&As[buf][row1 * 32 + sc1 * 8] = va1;                           \
            *(uint4*)&Bs[buf][row1 * 32 + sc1 * 8] = bb1;                           \
        } while (0)

    f32x4 acc[4][4];
    #pragma unroll
    for (int m = 0; m < 4; ++m)
        #pragma unroll
        for (int n = 0; n < 4; ++n)
            acc[m][n] = (f32x4){0.f, 0.f, 0.f, 0.f};

    LOAD_TILE(0);
    WRITE_TILE(0);
    __syncthreads();

    const int nk = K >> 5;
    for (int ki = 0; ki < nk; ++ki) {
        const int cur = ki & 1;
        if (ki + 1 < nk) LOAD_TILE((ki + 1) << 5);
        bf16x8 a[4], b[4];
        #pragma unroll
        for (int m = 0; m < 4; ++m) {
            int row = wr + m * 16 + r16;
            a[m] = *(const bf16x8*)&As[cur][row * 32 + ((kq ^ (row & 3)) * 8)];
        }
        #pragma unroll
        for (int n = 0; n < 4; ++n) {
            int row = wc + n * 16 + r16;
            b[n] = *(const bf16x8*)&Bs[cur][row * 32 + ((kq ^ (row & 3)) * 8)];
        }
        #pragma unroll
        for (int m = 0; m < 4; ++m)
            #pragma unroll
            for (int n = 0; n < 4; ++n)
                acc[m][n] = __builtin_amdgcn_mfma_f32_16x16x32_bf16(a[m], b[n], acc[m][n], 0, 0, 0);
        if (ki + 1 < nk) WRITE_TILE(cur ^ 1);
        __syncthreads();
    }
    #undef LOAD_TILE
    #undef WRITE_TILE

    #pragma unroll
    for (int m = 0; m < 4; ++m) {
        #pragma unroll
        for (int j = 0; j < 4; ++j) {
            size_t row = bm + wr + m * 16 + kq * 4 + j;
            #pragma unroll
            for (int n = 0; n < 4; ++n) {
                size_t col = bn + wc + n * 16 + r16;
                if (C_BF16) ((u16*)Cp)[row * Nn + col] = f2bf(acc[m][n][j]);
                else        ((float*)Cp)[row * Nn + col] = acc[m][n][j];
            }
        }
    }
}

// Fused per-graph aggregation + epilogue.
// agg[c][ch] = sum_r A[r][c] * m[r][ch], via dense 64x64 LDS adjacency + MFMA.
// Then out = relu(agg + v + bias).  B holds [m|v] (N x 256 f32).
template<int LAYER>
__global__ __launch_bounds__(256) void k_agg(const int* __restrict__ ei,
        const float* __restrict__ norm, const float* __restrict__ B,
        const float* __restrict__ bias, float* __restrict__ out0,
        float* __restrict__ out5, u16* __restrict__ xb) {
    __shared__ float A_s[64 * 65];   // [r][c], padded
    __shared__ u16   Ms[64 * 132];   // m bf16 [r][ch], padded
    const int g = blockIdx.x, t = threadIdx.x;
    const int lane = t & 63, w = t >> 6;
    const int r16 = lane & 15, kq = lane >> 4;
    const size_t nbase = (size_t)g * 64;

    #pragma unroll
    for (int i = t; i < 64 * 65; i += 256) A_s[i] = 0.f;
    #pragma unroll
    for (int i = t; i < 64 * 32; i += 256) {
        int row = i >> 5, c4 = (i & 31) << 2;
        float4 mv = *(const float4*)(B + (nbase + row) * 256 + c4);
        union { uint2 d; u16 s[4]; } p;
        p.s[0] = f2bf(mv.x); p.s[1] = f2bf(mv.y);
        p.s[2] = f2bf(mv.z); p.s[3] = f2bf(mv.w);
        *(uint2*)&Ms[row * 132 + c4] = p.d;
    }
    __syncthreads();
    {   // scatter 256 edges into A_s[r][c] (duplicates possible -> atomic)
        int e = g * 256 + t;
        int r = ei[e] & 63, c = ei[E_ + e] & 63;
        atomicAdd(&A_s[r * 65 + c], norm[e]);
    }
    __syncthreads();

    const int n0 = w * 32;           // wave's ch chunk
    f32x4 acc[4][2];
    #pragma unroll
    for (int mt = 0; mt < 4; ++mt)
        #pragma unroll
        for (int nt = 0; nt < 2; ++nt)
            acc[mt][nt] = (f32x4){0.f, 0.f, 0.f, 0.f};

    union bfr { bf16x8 v; u16 s[8]; };
    #pragma unroll
    for (int ks = 0; ks < 2; ++ks) {
        bfr a[4], b[2];
        #pragma unroll
        for (int mt = 0; mt < 4; ++mt)
            #pragma unroll
            for (int i = 0; i < 8; ++i)
                a[mt].s[i] = f2bf(A_s[(ks*32 + kq*8 + i) * 65 + mt*16 + r16]);
        #pragma unroll
        for (int nt = 0; nt < 2; ++nt)
            #pragma unroll
            for (int i = 0; i < 8; ++i)
                b[nt].s[i] = Ms[(ks*32 + kq*8 + i) * 132 + n0 + nt*16 + r16];
        #pragma unroll
        for (int mt = 0; mt < 4; ++mt)
            #pragma unroll
            for (int nt = 0; nt < 2; ++nt)
                acc[mt][nt] = __builtin_amdgcn_mfma_f32_16x16x32_bf16(a[mt].v, b[nt].v, acc[mt][nt], 0, 0, 0);
    }
    // epilogue: C row = output node (c), col = ch
    #pragma unroll
    for (int mt = 0; mt < 4; ++mt) {
        #pragma unroll
        for (int j = 0; j < 4; ++j) {
            int c = mt * 16 + kq * 4 + j;
            size_t node = nbase + c;
            #pragma unroll
            for (int nt = 0; nt < 2; ++nt) {
                int ch = n0 + nt * 16 + r16;
                float v = B[node * 256 + 128 + ch] + bias[ch];
                float r = fmaxf(acc[mt][nt][j] + v, 0.f);
                if (LAYER == 1) {
                    xb[node * 128 + ch] = f2bf(r);
                } else {
                    out0[node * 128 + ch] = r;
                    out5[node * 128 + ch] = r;
                    xb[node * 128 + ch] = f2bf(r);
                }
            }
        }
    }
}

// Fused GEMM3 + edge MLP, one block per graph, 512 threads = 8 waves.
// Phase 1: PQ[64][1024] = x2[64][128] @ Mwt[1024][128]^T into LDS (bf16),
//          with mb1 folded into P columns (col<512).
// Phase 2: pred[e] = mb2 + sum_j relu(P'[r][j] + Q[c][j]) * mw2[j]
//          lane-owns-edge, hidden split across half-waves (one shfl_xor(32)).
#define PQS 1032    // u16 stride; 2064 B/row = 516 dw, 516%32=4 -> 8-row bank period
__global__ __launch_bounds__(512) void k_pqedge(const u16* __restrict__ x2b,
        const u16* __restrict__ Mwt, const int* __restrict__ ei,
        const float* __restrict__ mb1, const float* __restrict__ mw2,
        const float* __restrict__ mb2, float* __restrict__ pred) {
    __shared__ u16 PQs[64 * PQS];       // 129 KB
    __shared__ float mw2s[512];
    const int g = blockIdx.x, t = threadIdx.x;
    const int lane = t & 63, w = t >> 6;
    const int r16 = lane & 15, kq = lane >> 4;
    const int nb = w * 128;             // wave's 128-col slice of PQ

    if (t < 128) *(float4*)&mw2s[t * 4] = *(const float4*)&mw2[t * 4];

    // ---- phase 1: PQ GEMM ----
    f32x4 acc[4][8];
    #pragma unroll
    for (int mt = 0; mt < 4; ++mt)
        #pragma unroll
        for (int nt = 0; nt < 8; ++nt)
            acc[mt][nt] = (f32x4){0.f, 0.f, 0.f, 0.f};

    #pragma unroll
    for (int ks = 0; ks < 4; ++ks) {
        const int k0 = ks * 32;
        bf16x8 a[4], b[8];
        #pragma unroll
        for (int mt = 0; mt < 4; ++mt)
            a[mt] = *(const bf16x8*)(x2b + ((size_t)g * 64 + mt * 16 + r16) * 128 + k0 + kq * 8);
        #pragma unroll
        for (int nt = 0; nt < 8; ++nt)
            b[nt] = *(const bf16x8*)(Mwt + (size_t)(nb + nt * 16 + r16) * 128 + k0 + kq * 8);
        #pragma unroll
        for (int mt = 0; mt < 4; ++mt)
            #pragma unroll
            for (int nt = 0; nt < 8; ++nt)
                acc[mt][nt] = __builtin_amdgcn_mfma_f32_16x16x32_bf16(a[mt], b[nt], acc[mt][nt], 0, 0, 0);
    }
    // epilogue: write bf16 to LDS, fold mb1 into P columns
    #pragma unroll
    for (int nt = 0; nt < 8; ++nt) {
        int col = nb + nt * 16 + r16;
        float bias = (col < HID) ? mb1[col] : 0.f;
        #pragma unroll
        for (int mt = 0; mt < 4; ++mt)
            #pragma unroll
            for (int j = 0; j < 4; ++j) {
                int row = mt * 16 + kq * 4 + j;
                PQs[row * PQS + col] = f2bf(acc[mt][nt][j] + bias);
            }
    }
    __syncthreads();

    // ---- phase 2: edge combine ----
    const int le = lane & 31, jh = lane >> 5;     // edge slot, hidden half
    const int e = g * 256 + w * 32 + le;
    const int r = ei[e] & 63, c = ei[E_ + e] & 63;
    const u16* pP = &PQs[r * PQS + jh * 256];
    const u16* pQ = &PQs[c * PQS + 512 + jh * 256];
    const float* pW = &mw2s[jh * 256];
    float s = 0.f;
    #pragma unroll 8
    for (int it = 0; it < 32; ++it) {
        uint4 up = *(const uint4*)(pP + it * 8);
        uint4 uq = *(const uint4*)(pQ + it * 8);
        float4 w0 = *(const float4*)(pW + it * 8);
        float4 w1 = *(const float4*)(pW + it * 8 + 4);
        u32 pu[4] = {up.x, up.y, up.z, up.w};
        u32 qu[4] = {uq.x, uq.y, uq.z, uq.w};
        float ww[8] = {w0.x,w0.y,w0.z,w0.w,w1.x,w1.y,w1.z,w1.w};
        #pragma unroll
        for (int k = 0; k < 4; ++k) {
            float p0 = bf2f(pu[k] & 0xffffu), p1 = bf2f(pu[k] >> 16);
            float q0 = bf2f(qu[k] & 0xffffu), q1 = bf2f(qu[k] >> 16);
            s += fmaxf(p0 + q0, 0.f) * ww[2*k];
            s += fmaxf(p1 + q1, 0.f) * ww[2*k + 1];
        }
    }
    s += __shfl_xor(s, 32, 64);
    if (lane < 32) pred[e] = s + mb2[0];
}

// one block per graph: stable bitonic sort (desc by pred, ties by idx asc),
// then write causal/conf gathers + the full pred copy.
__global__ __launch_bounds__(256) void k_sort(const float* __restrict__ pred,
        const int* __restrict__ ei, const float* __restrict__ ea,
        float* __restrict__ out) {
    __shared__ float key[256];
    __shared__ int   idx[256];
    int g = blockIdx.x, t = threadIdx.x;
    int ebase = g * EPG;
    float p = pred[ebase + t];
    key[t] = p; idx[t] = t;
    for (int k2 = 2; k2 <= 256; k2 <<= 1) {
        for (int j = k2 >> 1; j >= 1; j >>= 1) {
            __syncthreads();
            int ixj = t ^ j;
            if (ixj > t) {
                float ka = key[t], kb = key[ixj];
                int   ia = idx[t], ib = idx[ixj];
                bool up = ((t & k2) == 0);
                bool a_before_b = (ka > kb) || (ka == kb && ia < ib);
                bool do_swap = up ? !a_before_b : a_before_b;
                if (do_swap) { key[t] = kb; key[ixj] = ka; idx[t] = ib; idx[ixj] = ia; }
            }
        }
    }
    __syncthreads();
    int el = idx[t];
    int eg = ebase + el;
    float pv = key[t];
    float r = (float)ei[eg];
    float c = (float)ei[E_ + eg];
    float av = ea[eg];
    if (t < KSEL) {
        int oo = g * KSEL + t;
        out[OFF1 + oo]      = r;
        out[OFF1 + GK + oo] = c;
        out[OFF2 + oo]      = av;
        out[OFF3 + oo]      = pv;
    } else {
        int oo = g * KSEL + (t - KSEL);
        out[OFF6 + oo]      = r;
        out[OFF6 + GK + oo] = c;
        out[OFF7 + oo]      = av;
        out[OFF8 + oo]      = -pv;
    }
    out[OFF10 + ebase + t] = p;
}

__global__ void k_batch(const int* __restrict__ batch, float* __restrict__ out) {
    int i = blockIdx.x * 256 + threadIdx.x;
    if (i < N_) { float b = (float)batch[i]; out[OFF4 + i] = b; out[OFF9 + i] = b; }
}

extern "C" void kernel_launch(void* const* d_in, const int* in_sizes, int n_in,
                              void* d_out, int out_size, void* d_ws, size_t ws_size,
                              hipStream_t stream) {
    const float* x     = (const float*)d_in[0];
    const int*   ei    = (const int*)  d_in[1];
    const float* ea    = (const float*)d_in[2];
    const int*   batch = (const int*)  d_in[3];
    const float* W1    = (const float*)d_in[4];
    const float* V1    = (const float*)d_in[5];
    const float* b1    = (const float*)d_in[6];
    const float* W2    = (const float*)d_in[7];
    const float* V2    = (const float*)d_in[8];
    const float* b2    = (const float*)d_in[9];
    const float* mw1   = (const float*)d_in[10];
    const float* mb1   = (const float*)d_in[11];
    const float* mw2   = (const float*)d_in[12];
    const float* mb2   = (const float*)d_in[13];
    float* out = (float*)d_out;

    char* ws = (char*)d_ws;
    size_t o = 0;
    float* deg  = (float*)(ws + o); o += (size_t)N_ * 4;          // 256 KB
    float* norm = (float*)(ws + o); o += (size_t)E_ * 4;          // 1 MB
    float* pred = (float*)(ws + o); o += (size_t)E_ * 4;          // 1 MB
    u16* WV1t   = (u16*)(ws + o);   o += (size_t)256 * IN_CH * 2; // 384 KB
    u16* WV2t   = (u16*)(ws + o);   o += (size_t)256 * CH * 2;    // 64 KB
    u16* Mwt    = (u16*)(ws + o);   o += (size_t)1024 * CH * 2;   // 256 KB
    u16* x2b    = (u16*)(ws + o);   o += (size_t)N_ * CH * 2;     // 16 MB
    u16* x1b    = (u16*)(ws + o);   o += (size_t)N_ * CH * 2;     // 16 MB
    float* B    = (float*)(ws + o); o += (size_t)N_ * 256 * 4;    // 64 MB

    // degree / norm / weights
    hipMemsetAsync(deg, 0, (size_t)N_ * 4, stream);
    k_deg <<<E_/256, 256, 0, stream>>>(ei, ea, deg);
    k_dis <<<N_/256, 256, 0, stream>>>(deg);
    k_norm<<<E_/256, 256, 0, stream>>>(ei, ea, deg, norm);
    k_concat<<<768, 256, 0, stream>>>(W1, V1, W2, V2, mw1, WV1t, WV2t, Mwt);

    dim3 g1(N_/128, 256/128);
    // layer 1: B = [m|v] = x @ [W1|V1]  (A fp32 converted in staging)
    mfma_gemm<1,0><<<g1, 256, 0, stream>>>(x, WV1t, B, 256, IN_CH);
    k_agg<1><<<G_, 256, 0, stream>>>(ei, norm, B, b1, nullptr, nullptr, x1b);
    // layer 2
    mfma_gemm<0,0><<<g1, 256, 0, stream>>>(x1b, WV2t, B, 256, CH);
    k_agg<2><<<G_, 256, 0, stream>>>(ei, norm, B, b2, out + OFF0, out + OFF5, x2b);
    // fused edge MLP: per-graph PQ GEMM in LDS + edge combine
    k_pqedge<<<G_, 512, 0, stream>>>(x2b, Mwt, ei, mb1, mw2, mb2, pred);
    // per-graph top-K partition + outputs
    k_sort<<<G_, 256, 0, stream>>>(pred, ei, ea, out);
    k_batch<<<N_/256, 256, 0, stream>>>(batch, out);
}

// Round 7
// 247.079 us; speedup vs baseline: 1.5946x; 1.1145x over previous
//
#include <hip/hip_runtime.h>
#include <hip/hip_bf16.h>
#include <stdint.h>

#define G_    1024
#define NPG   64
#define EPG   256
#define N_    (G_*NPG)     // 65536
#define E_    (G_*EPG)     // 262144
#define IN_CH 768
#define CH    128
#define KSEL  128
#define HID   512          // 4*CH

// ---- output layout (element offsets, all float32) ----
#define NCH  (N_*CH)       // 8388608
#define GK   (G_*KSEL)     // 131072
#define OFF0 0
#define OFF1 (OFF0 + NCH)
#define OFF2 (OFF1 + 2*GK)
#define OFF3 (OFF2 + GK)
#define OFF4 (OFF3 + GK)
#define OFF5 (OFF4 + N_)
#define OFF6 (OFF5 + NCH)
#define OFF7 (OFF6 + 2*GK)
#define OFF8 (OFF7 + GK)
#define OFF9 (OFF8 + GK)
#define OFF10 (OFF9 + N_)

typedef unsigned short u16;
typedef unsigned int   u32;
typedef __attribute__((ext_vector_type(8))) short bf16x8;
typedef __attribute__((ext_vector_type(4))) float f32x4;

__device__ __forceinline__ u16 f2bf(float x) {
    union { float f; u32 u; } v; v.f = x;
    u32 r = v.u + 0x7fffu + ((v.u >> 16) & 1u);   // RNE
    return (u16)(r >> 16);
}
__device__ __forceinline__ float bf2f(u32 h) {
    union { u32 u; float f; } v; v.u = h << 16; return v.f;
}
__device__ __forceinline__ u16 bfc(float x) {   // native cvt (compiler fuses to v_cvt_pk_bf16_f32)
    __hip_bfloat16 h = __float2bfloat16(x);
    return *reinterpret_cast<u16*>(&h);
}

__global__ void k_deg(const int* __restrict__ ei, const float* __restrict__ ea,
                      float* __restrict__ deg) {
    int e = blockIdx.x * 256 + threadIdx.x;
    if (e < E_) atomicAdd(&deg[ei[E_ + e]], ea[e]);
}

__global__ void k_dis(float* __restrict__ deg) {
    int i = blockIdx.x * 256 + threadIdx.x;
    if (i < N_) { float d = deg[i]; deg[i] = d > 0.f ? 1.0f / sqrtf(d) : 0.f; }
}

__global__ void k_norm(const int* __restrict__ ei, const float* __restrict__ ea,
                       const float* __restrict__ dis, float* __restrict__ norm) {
    int e = blockIdx.x * 256 + threadIdx.x;
    if (e < E_) norm[e] = dis[ei[e]] * ea[e] * dis[ei[E_ + e]];
}

// Build TRANSPOSED bf16 weights (row = output col, cols = K).
__global__ void k_concat(const float* __restrict__ W1, const float* __restrict__ V1,
                         const float* __restrict__ W2, const float* __restrict__ V2,
                         const float* __restrict__ mw1,
                         u16* __restrict__ WV1t, u16* __restrict__ WV2t,
                         u16* __restrict__ Mwt) {
    int i = blockIdx.x * 256 + threadIdx.x;
    if (i < 256 * IN_CH) {
        int c = i / IN_CH, r = i - c * IN_CH;
        WV1t[i] = f2bf(c < CH ? W1[r*CH + c] : V1[r*CH + (c - CH)]);
    }
    if (i < 256 * CH) {
        int c = i >> 7, r = i & 127;
        WV2t[i] = f2bf(c < CH ? W2[r*CH + c] : V2[r*CH + (c - CH)]);
    }
    if (i < 1024 * CH) {
        int c = i >> 7, r = i & 127;
        Mwt[i] = f2bf(c < HID ? mw1[r*HID + c] : mw1[(CH + r)*HID + (c - HID)]);
    }
}

// Layer-1 GEMM: C(N x 256 bf16) = bf16(x(N x 768 f32)) @ WV1t^T.
// m97-style staging: A f32 tile (128x32) -> LDS via global_load_lds(16B),
// linear LDS dest + XOR-swizzled global SOURCE, XOR-swizzled ds_read (rule #21).
// B fragments direct from global (weights L2-resident), prefetched 1 step.
__global__ __launch_bounds__(256) void k_gemm1(const float* __restrict__ Ap,
        const u16* __restrict__ Bt, u16* __restrict__ Cp) {
    __shared__ float As[2][128 * 32];     // 2 x 16 KB
    const int t = threadIdx.x;
    const int lane = t & 63, w = t >> 6;
    const int wr = (w >> 1) << 6, wc = (w & 1) << 6;
    const size_t bm = (size_t)blockIdx.x * 128;
    const size_t bn = (size_t)blockIdx.y * 128;
    const int r16 = lane & 15, kq = lane >> 4;

    // staging chunks: 1024 granules(16B)/tile; thread handles i*256 + w*64 + lane
    int cid[4], grow[4], gcol[4];
    #pragma unroll
    for (int i = 0; i < 4; ++i) {
        int c = i * 256 + w * 64 + lane;
        cid[i] = c;
        int row = c >> 3, sl = c & 7;
        grow[i] = row;
        gcol[i] = (sl ^ (row & 7)) * 4;   // inverse-swizzled source granule (f32 idx)
    }

    f32x4 acc[4][4];
    #pragma unroll
    for (int m = 0; m < 4; ++m)
        #pragma unroll
        for (int n = 0; n < 4; ++n)
            acc[m][n] = (f32x4){0.f, 0.f, 0.f, 0.f};

    #define STAGE(buf, k0)                                                      \
        do {                                                                    \
            _Pragma("unroll")                                                   \
            for (int i = 0; i < 4; ++i) {                                       \
                const float* src = Ap + (bm + grow[i]) * (size_t)IN_CH + (k0) + gcol[i]; \
                __builtin_amdgcn_global_load_lds(                               \
                    (const __attribute__((address_space(1))) void*)src,         \
                    (__attribute__((address_space(3))) void*)&As[buf][cid[i] * 4], \
                    16, 0, 0);                                                  \
            }                                                                   \
        } while (0)

    #define LOADB(bv, k0)                                                       \
        do {                                                                    \
            _Pragma("unroll")                                                   \
            for (int n = 0; n < 4; ++n)                                         \
                bv[n] = *(const bf16x8*)(Bt + (bn + wc + n * 16 + r16) * (size_t)IN_CH + (k0) + kq * 8); \
        } while (0)

    STAGE(0, 0);
    bf16x8 bc[4];
    LOADB(bc, 0);
    __syncthreads();

    const int nk = IN_CH / 32;     // 24
    int buf = 0;
    for (int ki = 0; ki < nk; ++ki) {
        bf16x8 bnx[4];
        if (ki + 1 < nk) {
            STAGE(buf ^ 1, (ki + 1) * 32);     // in flight across this iter
            LOADB(bnx, (ki + 1) * 32);
        }
        bf16x8 a[4];
        #pragma unroll
        for (int m = 0; m < 4; ++m) {
            int row = wr + m * 16 + r16;
            int xr = row & 7;
            const float* base = &As[buf][row * 32];
            float4 q0 = *(const float4*)(base + (((2 * kq)     ^ xr) * 4));
            float4 q1 = *(const float4*)(base + (((2 * kq + 1) ^ xr) * 4));
            union { bf16x8 v; u16 s[8]; } pk;
            pk.s[0] = bfc(q0.x); pk.s[1] = bfc(q0.y); pk.s[2] = bfc(q0.z); pk.s[3] = bfc(q0.w);
            pk.s[4] = bfc(q1.x); pk.s[5] = bfc(q1.y); pk.s[6] = bfc(q1.z); pk.s[7] = bfc(q1.w);
            a[m] = pk.v;
        }
        #pragma unroll
        for (int m = 0; m < 4; ++m)
            #pragma unroll
            for (int n = 0; n < 4; ++n)
                acc[m][n] = __builtin_amdgcn_mfma_f32_16x16x32_bf16(a[m], bc[n], acc[m][n], 0, 0, 0);
        if (ki + 1 < nk) {
            #pragma unroll
            for (int n = 0; n < 4; ++n) bc[n] = bnx[n];
        }
        __syncthreads();      // drains global_load_lds for buf^1
        buf ^= 1;
    }
    #undef STAGE
    #undef LOADB

    // C/D: col = lane&15, row = (lane>>4)*4 + reg
    #pragma unroll
    for (int m = 0; m < 4; ++m)
        #pragma unroll
        for (int j = 0; j < 4; ++j) {
            size_t row = bm + wr + m * 16 + kq * 4 + j;
            #pragma unroll
            for (int n = 0; n < 4; ++n) {
                size_t col = bn + wc + n * 16 + r16;
                Cp[row * 256 + col] = f2bf(acc[m][n][j]);
            }
        }
}

// Layer-1 aggregation + epilogue (B now bf16 [N][256] = [m|v]).
__global__ __launch_bounds__(256) void k_agg1(const int* __restrict__ ei,
        const float* __restrict__ norm, const u16* __restrict__ Bb,
        const float* __restrict__ bias, u16* __restrict__ x1b) {
    __shared__ float A_s[64 * 65];
    __shared__ u16   Ms[64 * 132];
    const int g = blockIdx.x, t = threadIdx.x;
    const int lane = t & 63, w = t >> 6;
    const int r16 = lane & 15, kq = lane >> 4;
    const size_t nbase = (size_t)g * 64;

    for (int i = t; i < 64 * 65; i += 256) A_s[i] = 0.f;
    for (int i = t; i < 64 * 32; i += 256) {
        int row = i >> 5, c4 = (i & 31) << 2;
        *(uint2*)&Ms[row * 132 + c4] = *(const uint2*)(Bb + (nbase + row) * 256 + c4);
    }
    __syncthreads();
    { int e = g * 256 + t;
      atomicAdd(&A_s[(ei[e] & 63) * 65 + (ei[E_ + e] & 63)], norm[e]); }
    __syncthreads();

    const int n0 = w * 32;
    f32x4 acc[4][2];
    #pragma unroll
    for (int mt = 0; mt < 4; ++mt)
        #pragma unroll
        for (int nt = 0; nt < 2; ++nt)
            acc[mt][nt] = (f32x4){0.f, 0.f, 0.f, 0.f};

    union bfr { bf16x8 v; u16 s[8]; };
    #pragma unroll
    for (int ks = 0; ks < 2; ++ks) {
        bfr a[4], b[2];
        #pragma unroll
        for (int mt = 0; mt < 4; ++mt)
            #pragma unroll
            for (int i = 0; i < 8; ++i)
                a[mt].s[i] = f2bf(A_s[(ks*32 + kq*8 + i) * 65 + mt*16 + r16]);
        #pragma unroll
        for (int nt = 0; nt < 2; ++nt)
            #pragma unroll
            for (int i = 0; i < 8; ++i)
                b[nt].s[i] = Ms[(ks*32 + kq*8 + i) * 132 + n0 + nt*16 + r16];
        #pragma unroll
        for (int mt = 0; mt < 4; ++mt)
            #pragma unroll
            for (int nt = 0; nt < 2; ++nt)
                acc[mt][nt] = __builtin_amdgcn_mfma_f32_16x16x32_bf16(a[mt].v, b[nt].v, acc[mt][nt], 0, 0, 0);
    }
    #pragma unroll
    for (int mt = 0; mt < 4; ++mt)
        #pragma unroll
        for (int j = 0; j < 4; ++j) {
            int c = mt * 16 + kq * 4 + j;
            size_t node = nbase + c;
            #pragma unroll
            for (int nt = 0; nt < 2; ++nt) {
                int ch = n0 + nt * 16 + r16;
                float v = bf2f(Bb[node * 256 + 128 + ch]) + bias[ch];
                x1b[node * 128 + ch] = f2bf(fmaxf(acc[mt][nt][j] + v, 0.f));
            }
        }
}

// Fused layer-2: per-graph GEMM (mv = x1g @ WV2t^T, 64x256) into LDS,
// then dense-adjacency aggregation + epilogue. Kills the 128 MB B round-trip.
__global__ __launch_bounds__(256) void k_l2agg(const u16* __restrict__ x1b,
        const u16* __restrict__ Wt, const int* __restrict__ ei,
        const float* __restrict__ norm, const float* __restrict__ bias,
        float* __restrict__ out0, float* __restrict__ out5,
        u16* __restrict__ xb) {
    __shared__ float A_s[64 * 65];      // 16.6 KB
    __shared__ u16   MVs[64 * 264];     // 33.8 KB, cols 0..127 = m, 128..255 = v
    const int g = blockIdx.x, t = threadIdx.x;
    const int lane = t & 63, w = t >> 6;
    const int r16 = lane & 15, kq = lane >> 4;
    const size_t nbase = (size_t)g * 64;

    for (int i = t; i < 64 * 65; i += 256) A_s[i] = 0.f;
    __syncthreads();
    { int e = g * 256 + t;
      atomicAdd(&A_s[(ei[e] & 63) * 65 + (ei[E_ + e] & 63)], norm[e]); }

    // GEMM phase: wave w computes all 64 rows x cols [wc, wc+64)
    const int wc = w * 64;
    f32x4 acc[4][4];
    #pragma unroll
    for (int mt = 0; mt < 4; ++mt)
        #pragma unroll
        for (int n = 0; n < 4; ++n)
            acc[mt][n] = (f32x4){0.f, 0.f, 0.f, 0.f};
    #pragma unroll
    for (int ks = 0; ks < 4; ++ks) {
        int k0 = ks * 32;
        bf16x8 a[4], b[4];
        #pragma unroll
        for (int mt = 0; mt < 4; ++mt)
            a[mt] = *(const bf16x8*)(x1b + (nbase + mt * 16 + r16) * 128 + k0 + kq * 8);
        #pragma unroll
        for (int n = 0; n < 4; ++n)
            b[n] = *(const bf16x8*)(Wt + (size_t)(wc + n * 16 + r16) * 128 + k0 + kq * 8);
        #pragma unroll
        for (int mt = 0; mt < 4; ++mt)
            #pragma unroll
            for (int n = 0; n < 4; ++n)
                acc[mt][n] = __builtin_amdgcn_mfma_f32_16x16x32_bf16(a[mt], b[n], acc[mt][n], 0, 0, 0);
    }
    #pragma unroll
    for (int mt = 0; mt < 4; ++mt)
        #pragma unroll
        for (int j = 0; j < 4; ++j) {
            int row = mt * 16 + kq * 4 + j;
            #pragma unroll
            for (int n = 0; n < 4; ++n)
                MVs[row * 264 + wc + n * 16 + r16] = f2bf(acc[mt][n][j]);
        }
    __syncthreads();

    // aggregation phase (same as k_agg): ag = A^T @ m
    const int n0 = w * 32;
    f32x4 ag[4][2];
    #pragma unroll
    for (int mt = 0; mt < 4; ++mt)
        #pragma unroll
        for (int nt = 0; nt < 2; ++nt)
            ag[mt][nt] = (f32x4){0.f, 0.f, 0.f, 0.f};
    union bfr { bf16x8 v; u16 s[8]; };
    #pragma unroll
    for (int ks = 0; ks < 2; ++ks) {
        bfr a[4], b[2];
        #pragma unroll
        for (int mt = 0; mt < 4; ++mt)
            #pragma unroll
            for (int i = 0; i < 8; ++i)
                a[mt].s[i] = f2bf(A_s[(ks*32 + kq*8 + i) * 65 + mt*16 + r16]);
        #pragma unroll
        for (int nt = 0; nt < 2; ++nt)
            #pragma unroll
            for (int i = 0; i < 8; ++i)
                b[nt].s[i] = MVs[(ks*32 + kq*8 + i) * 264 + n0 + nt*16 + r16];
        #pragma unroll
        for (int mt = 0; mt < 4; ++mt)
            #pragma unroll
            for (int nt = 0; nt < 2; ++nt)
                ag[mt][nt] = __builtin_amdgcn_mfma_f32_16x16x32_bf16(a[mt].v, b[nt].v, ag[mt][nt], 0, 0, 0);
    }
    #pragma unroll
    for (int mt = 0; mt < 4; ++mt)
        #pragma unroll
        for (int j = 0; j < 4; ++j) {
            int c = mt * 16 + kq * 4 + j;
            size_t node = nbase + c;
            #pragma unroll
            for (int nt = 0; nt < 2; ++nt) {
                int ch = n0 + nt * 16 + r16;
                float v = bf2f(MVs[c * 264 + 128 + ch]) + bias[ch];
                float r = fmaxf(ag[mt][nt][j] + v, 0.f);
                out0[node * 128 + ch] = r;
                out5[node * 128 + ch] = r;
                xb[node * 128 + ch] = f2bf(r);
            }
        }
}

// Fused GEMM3 + edge MLP, one block per graph, 512 threads = 8 waves.
#define PQS 1032
__global__ __launch_bounds__(512) void k_pqedge(const u16* __restrict__ x2b,
        const u16* __restrict__ Mwt, const int* __restrict__ ei,
        const float* __restrict__ mb1, const float* __restrict__ mw2,
        const float* __restrict__ mb2, float* __restrict__ pred) {
    __shared__ u16 PQs[64 * PQS];
    __shared__ float mw2s[512];
    const int g = blockIdx.x, t = threadIdx.x;
    const int lane = t & 63, w = t >> 6;
    const int r16 = lane & 15, kq = lane >> 4;
    const int nb = w * 128;

    if (t < 128) *(float4*)&mw2s[t * 4] = *(const float4*)&mw2[t * 4];

    f32x4 acc[4][8];
    #pragma unroll
    for (int mt = 0; mt < 4; ++mt)
        #pragma unroll
        for (int nt = 0; nt < 8; ++nt)
            acc[mt][nt] = (f32x4){0.f, 0.f, 0.f, 0.f};

    #pragma unroll
    for (int ks = 0; ks < 4; ++ks) {
        const int k0 = ks * 32;
        bf16x8 a[4], b[8];
        #pragma unroll
        for (int mt = 0; mt < 4; ++mt)
            a[mt] = *(const bf16x8*)(x2b + ((size_t)g * 64 + mt * 16 + r16) * 128 + k0 + kq * 8);
        #pragma unroll
        for (int nt = 0; nt < 8; ++nt)
            b[nt] = *(const bf16x8*)(Mwt + (size_t)(nb + nt * 16 + r16) * 128 + k0 + kq * 8);
        #pragma unroll
        for (int mt = 0; mt < 4; ++mt)
            #pragma unroll
            for (int nt = 0; nt < 8; ++nt)
                acc[mt][nt] = __builtin_amdgcn_mfma_f32_16x16x32_bf16(a[mt], b[nt], acc[mt][nt], 0, 0, 0);
    }
    #pragma unroll
    for (int nt = 0; nt < 8; ++nt) {
        int col = nb + nt * 16 + r16;
        float bias = (col < HID) ? mb1[col] : 0.f;
        #pragma unroll
        for (int mt = 0; mt < 4; ++mt)
            #pragma unroll
            for (int j = 0; j < 4; ++j) {
                int row = mt * 16 + kq * 4 + j;
                PQs[row * PQS + col] = f2bf(acc[mt][nt][j] + bias);
            }
    }
    __syncthreads();

    const int le = lane & 31, jh = lane >> 5;
    const int e = g * 256 + w * 32 + le;
    const int r = ei[e] & 63, c = ei[E_ + e] & 63;
    const u16* pP = &PQs[r * PQS + jh * 256];
    const u16* pQ = &PQs[c * PQS + 512 + jh * 256];
    const float* pW = &mw2s[jh * 256];
    float s = 0.f;
    #pragma unroll 8
    for (int it = 0; it < 32; ++it) {
        uint4 up = *(const uint4*)(pP + it * 8);
        uint4 uq = *(const uint4*)(pQ + it * 8);
        float4 w0 = *(const float4*)(pW + it * 8);
        float4 w1 = *(const float4*)(pW + it * 8 + 4);
        u32 pu[4] = {up.x, up.y, up.z, up.w};
        u32 qu[4] = {uq.x, uq.y, uq.z, uq.w};
        float ww[8] = {w0.x,w0.y,w0.z,w0.w,w1.x,w1.y,w1.z,w1.w};
        #pragma unroll
        for (int k = 0; k < 4; ++k) {
            float p0 = bf2f(pu[k] & 0xffffu), p1 = bf2f(pu[k] >> 16);
            float q0 = bf2f(qu[k] & 0xffffu), q1 = bf2f(qu[k] >> 16);
            s += fmaxf(p0 + q0, 0.f) * ww[2*k];
            s += fmaxf(p1 + q1, 0.f) * ww[2*k + 1];
        }
    }
    s += __shfl_xor(s, 32, 64);
    if (lane < 32) pred[e] = s + mb2[0];
}

// one block per graph: stable bitonic sort (desc by pred, ties by idx asc)
__global__ __launch_bounds__(256) void k_sort(const float* __restrict__ pred,
        const int* __restrict__ ei, const float* __restrict__ ea,
        float* __restrict__ out) {
    __shared__ float key[256];
    __shared__ int   idx[256];
    int g = blockIdx.x, t = threadIdx.x;
    int ebase = g * EPG;
    float p = pred[ebase + t];
    key[t] = p; idx[t] = t;
    for (int k2 = 2; k2 <= 256; k2 <<= 1) {
        for (int j = k2 >> 1; j >= 1; j >>= 1) {
            __syncthreads();
            int ixj = t ^ j;
            if (ixj > t) {
                float ka = key[t], kb = key[ixj];
                int   ia = idx[t], ib = idx[ixj];
                bool up = ((t & k2) == 0);
                bool a_before_b = (ka > kb) || (ka == kb && ia < ib);
                bool do_swap = up ? !a_before_b : a_before_b;
                if (do_swap) { key[t] = kb; key[ixj] = ka; idx[t] = ib; idx[ixj] = ia; }
            }
        }
    }
    __syncthreads();
    int el = idx[t];
    int eg = ebase + el;
    float pv = key[t];
    float r = (float)ei[eg];
    float c = (float)ei[E_ + eg];
    float av = ea[eg];
    if (t < KSEL) {
        int oo = g * KSEL + t;
        out[OFF1 + oo]      = r;
        out[OFF1 + GK + oo] = c;
        out[OFF2 + oo]      = av;
        out[OFF3 + oo]      = pv;
    } else {
        int oo = g * KSEL + (t - KSEL);
        out[OFF6 + oo]      = r;
        out[OFF6 + GK + oo] = c;
        out[OFF7 + oo]      = av;
        out[OFF8 + oo]      = -pv;
    }
    out[OFF10 + ebase + t] = p;
}

__global__ void k_batch(const int* __restrict__ batch, float* __restrict__ out) {
    int i = blockIdx.x * 256 + threadIdx.x;
    if (i < N_) { float b = (float)batch[i]; out[OFF4 + i] = b; out[OFF9 + i] = b; }
}

extern "C" void kernel_launch(void* const* d_in, const int* in_sizes, int n_in,
                              void* d_out, int out_size, void* d_ws, size_t ws_size,
                              hipStream_t stream) {
    const float* x     = (const float*)d_in[0];
    const int*   ei    = (const int*)  d_in[1];
    const float* ea    = (const float*)d_in[2];
    const int*   batch = (const int*)  d_in[3];
    const float* W1    = (const float*)d_in[4];
    const float* V1    = (const float*)d_in[5];
    const float* b1    = (const float*)d_in[6];
    const float* W2    = (const float*)d_in[7];
    const float* V2    = (const float*)d_in[8];
    const float* b2    = (const float*)d_in[9];
    const float* mw1   = (const float*)d_in[10];
    const float* mb1   = (const float*)d_in[11];
    const float* mw2   = (const float*)d_in[12];
    const float* mb2   = (const float*)d_in[13];
    float* out = (float*)d_out;

    char* ws = (char*)d_ws;
    size_t o = 0;
    float* deg  = (float*)(ws + o); o += (size_t)N_ * 4;          // 256 KB
    float* norm = (float*)(ws + o); o += (size_t)E_ * 4;          // 1 MB
    float* pred = (float*)(ws + o); o += (size_t)E_ * 4;          // 1 MB
    u16* WV1t   = (u16*)(ws + o);   o += (size_t)256 * IN_CH * 2; // 384 KB
    u16* WV2t   = (u16*)(ws + o);   o += (size_t)256 * CH * 2;    // 64 KB
    u16* Mwt    = (u16*)(ws + o);   o += (size_t)1024 * CH * 2;   // 256 KB
    u16* x2b    = (u16*)(ws + o);   o += (size_t)N_ * CH * 2;     // 16 MB
    u16* x1b    = (u16*)(ws + o);   o += (size_t)N_ * CH * 2;     // 16 MB
    u16* B1b    = (u16*)(ws + o);   o += (size_t)N_ * 256 * 2;    // 32 MB

    // degree / norm / weights
    hipMemsetAsync(deg, 0, (size_t)N_ * 4, stream);
    k_deg <<<E_/256, 256, 0, stream>>>(ei, ea, deg);
    k_dis <<<N_/256, 256, 0, stream>>>(deg);
    k_norm<<<E_/256, 256, 0, stream>>>(ei, ea, deg, norm);
    k_concat<<<768, 256, 0, stream>>>(W1, V1, W2, V2, mw1, WV1t, WV2t, Mwt);

    // layer 1: B1b = bf16([m|v]) = x @ [W1|V1]
    dim3 g1(N_/128, 2);
    k_gemm1<<<g1, 256, 0, stream>>>(x, WV1t, B1b);
    k_agg1<<<G_, 256, 0, stream>>>(ei, norm, B1b, b1, x1b);
    // layer 2 fused: per-graph GEMM + aggregation -> x2 (both slots) + x2b
    k_l2agg<<<G_, 256, 0, stream>>>(x1b, WV2t, ei, norm, b2, out + OFF0, out + OFF5, x2b);
    // fused edge MLP
    k_pqedge<<<G_, 512, 0, stream>>>(x2b, Mwt, ei, mb1, mw2, mb2, pred);
    // per-graph top-K partition + outputs
    k_sort<<<G_, 256, 0, stream>>>(pred, ei, ea, out);
    k_batch<<<N_/256, 256, 0, stream>>>(batch, out);
}